// Round 1
// baseline (691.455 us; speedup 1.0000x reference)
//
#include <hip/hip_runtime.h>

typedef _Float16 f16;
typedef _Float16 f16x2 __attribute__((ext_vector_type(2)));
typedef _Float16 f16x4 __attribute__((ext_vector_type(4)));
typedef _Float16 f16x8 __attribute__((ext_vector_type(8)));
typedef float f32x4 __attribute__((ext_vector_type(4)));

#define MFMA_16x16x32(a, b, c) __builtin_amdgcn_mfma_f32_16x16x32_f16((a), (b), (c), 0, 0, 0)

// Problem constants: B=2 S=2048 H=1024 HEADS=16 KD=64 VDIM=2048 HD=128
// M = B*S = 4096. qkvg row layout: [q(1024) | k(1024) | v(2048) | g(2048)] = 6144 cols.

// ---------------------------------------------------------------- casts
__global__ void k_cast_x(const float* __restrict__ x, f16* __restrict__ xh) {
  size_t i = ((size_t)blockIdx.x * 256 + threadIdx.x) * 4;
  float4 v = *(const float4*)(x + i);
  f16x4 r = { (f16)v.x, (f16)v.y, (f16)v.z, (f16)v.w };
  *(f16x4*)(xh + i) = r;
}

__global__ void k_cast_w1(const float* __restrict__ Wq, const float* __restrict__ Wk,
                          const float* __restrict__ Wv, const float* __restrict__ Wg,
                          f16* __restrict__ W1) {
  int u = blockIdx.x * 256 + threadIdx.x;   // 6144*256 threads, 4 elems each
  int row = u >> 8;
  int c = (u & 255) * 4;
  const float* src; float sc = 1.0f;
  if (row < 1024)       { src = Wq + (size_t)row * 1024; }
  else if (row < 2048)  { src = Wk + (size_t)(row - 1024) * 1024; sc = 0.125f; } // fold kd^-0.5
  else if (row < 4096)  { src = Wv + (size_t)(row - 2048) * 1024; }
  else                  { src = Wg + (size_t)(row - 4096) * 1024; }
  float4 v = *(const float4*)(src + c);
  f16x4 r = { (f16)(v.x * sc), (f16)(v.y * sc), (f16)(v.z * sc), (f16)(v.w * sc) };
  *(f16x4*)(W1 + (size_t)row * 1024 + c) = r;
}

__global__ void k_cast_wo(const float* __restrict__ Wo, f16* __restrict__ Woh) {
  size_t i = ((size_t)blockIdx.x * 256 + threadIdx.x) * 4;
  float4 v = *(const float4*)(Wo + i);
  f16x4 r = { (f16)v.x, (f16)v.y, (f16)v.z, (f16)v.w };
  *(f16x4*)(Woh + i) = r;
}

// ---------------------------------------------------------------- RoPE on q,k halves
__global__ void k_rope(f16* __restrict__ qkvg, const float* __restrict__ sinp,
                       const float* __restrict__ cosp) {
  int u = blockIdx.x * 256 + threadIdx.x;   // 4096 rows * 1024 pairs
  int row = u >> 10;
  int col = (u & 1023) * 2;                 // even col in [0,2048)
  int s = row & 2047;
  int d = col & 63;                          // index within head (kd=64)
  f16x2* p = (f16x2*)(qkvg + (size_t)row * 6144 + col);
  f16x2 xv = *p;
  float xe = (float)xv[0], xo = (float)xv[1];
  float se = sinp[s * 64 + d], so = sinp[s * 64 + d + 1];
  float ce = cosp[s * 64 + d], co = cosp[s * 64 + d + 1];
  f16x2 r = { (f16)(xe * ce - xo * se), (f16)(xo * co + xe * so) };
  *p = r;
}

// ---------------------------------------------------------------- GEMM  C[m][n] = sum_k A[m][k]*Bw[n][k]
// A: M x K, Bw: N x K (B-transposed layout), C: M x N. 128x128 block tile, BK=64, 4 waves.
template <typename OutT>
__global__ __launch_bounds__(256, 2)
void k_gemm_bt(const f16* __restrict__ A, const f16* __restrict__ Bw,
               OutT* __restrict__ C, int M, int N, int K) {
  constexpr int LDT = 72;                    // 64 + 8 pad: breaks row-bank aliasing
  __shared__ f16 As[128 * LDT];
  __shared__ f16 Bs[128 * LDT];
  const int tid = threadIdx.x;
  const int lane = tid & 63, w = tid >> 6;
  const int quad = lane >> 4, rm = lane & 15;
  const int mt = blockIdx.y, nt = blockIdx.x;
  const f16* Ab = A + (size_t)mt * 128 * K;
  const f16* Bb = Bw + (size_t)nt * 128 * K;
  f32x4 acc[2][8];
#pragma unroll
  for (int m = 0; m < 2; ++m)
#pragma unroll
    for (int n = 0; n < 8; ++n) acc[m][n] = (f32x4){0.f, 0.f, 0.f, 0.f};

  const int r0 = tid >> 3;                   // 0..31
  const int c8 = (tid & 7) * 8;              // 0..56

  for (int k0 = 0; k0 < K; k0 += 64) {
    __syncthreads();
#pragma unroll
    for (int p = 0; p < 4; ++p) {
      int r = r0 + p * 32;
      *(uint4*)(&As[r * LDT + c8]) = *(const uint4*)(Ab + (size_t)r * K + k0 + c8);
      *(uint4*)(&Bs[r * LDT + c8]) = *(const uint4*)(Bb + (size_t)r * K + k0 + c8);
    }
    __syncthreads();
#pragma unroll
    for (int kk = 0; kk < 64; kk += 32) {
      const int ko = kk + quad * 8;
      f16x8 a0 = *(const f16x8*)(&As[(w * 32 + rm) * LDT + ko]);
      f16x8 a1 = *(const f16x8*)(&As[(w * 32 + 16 + rm) * LDT + ko]);
#pragma unroll
      for (int n = 0; n < 8; ++n) {
        f16x8 bf = *(const f16x8*)(&Bs[(n * 16 + rm) * LDT + ko]);
        acc[0][n] = MFMA_16x16x32(a0, bf, acc[0][n]);
        acc[1][n] = MFMA_16x16x32(a1, bf, acc[1][n]);
      }
    }
  }
#pragma unroll
  for (int m = 0; m < 2; ++m)
#pragma unroll
    for (int n = 0; n < 8; ++n)
#pragma unroll
      for (int r = 0; r < 4; ++r) {
        int row = mt * 128 + w * 32 + m * 16 + quad * 4 + r;  // C/D: row = quad*4+reg
        int col = nt * 128 + n * 16 + rm;                     //      col = lane&15
        C[(size_t)row * N + col] = (OutT)acc[m][n][r];
      }
}

// ---------------------------------------------------------------- fused retention attention
// grid (16 s-blocks, 16 heads, 2 batch), 256 threads. Each block: 128 q-rows; wave: 32 rows.
// Streams t in chunks of 32 up to the causal boundary. Epilogue: denom, RMS over hd=128, silu(g).
__device__ __forceinline__ int vt_off(int d) { return d * 40 + (d >> 3) * 8; }  // skewed rows, 16B-aligned

__global__ __launch_bounds__(256, 2)
void k_attn(const f16* __restrict__ qkvg, f16* __restrict__ act) {
  constexpr int LDK = 72;
  constexpr int LDP = 40;
  __shared__ f16 Ks[32 * LDK];
  __shared__ f16 Vt[5240];            // Vt[d][t], row start = vt_off(d)
  __shared__ f16 Ps[4][32 * LDP];     // per-wave P staging (C-layout -> A-layout round trip)
  const int tid = threadIdx.x;
  const int lane = tid & 63, w = tid >> 6;
  const int quad = lane >> 4, rm = lane & 15;
  int bx = blockIdx.x;
  if (blockIdx.z) bx = 15 - bx;       // pair heavy+light s-blocks across the two batch dispatd waves
  const int h = blockIdx.y, b = blockIdx.z;
  const int s_blk = bx * 128;
  const size_t ld = 6144;
  const f16* base = qkvg + (size_t)b * 2048 * ld;
  const float logd = logf(1.0f - exp2f(-5.0f - (float)h));

  f16x8 qa[2][2];
#pragma unroll
  for (int m = 0; m < 2; ++m) {
    int row = s_blk + w * 32 + m * 16 + rm;
#pragma unroll
    for (int kh = 0; kh < 2; ++kh)
      qa[m][kh] = *(const f16x8*)(base + (size_t)row * ld + h * 64 + kh * 32 + quad * 8);
  }
  int voff[8];
#pragma unroll
  for (int n = 0; n < 8; ++n) voff[n] = vt_off(n * 16 + rm) + quad * 8;

  f32x4 od[2][8];
#pragma unroll
  for (int m = 0; m < 2; ++m)
#pragma unroll
    for (int n = 0; n < 8; ++n) od[m][n] = (f32x4){0.f, 0.f, 0.f, 0.f};
  float den[2][4] = {{0.f, 0.f, 0.f, 0.f}, {0.f, 0.f, 0.f, 0.f}};

  const int tmax = s_blk + 128;
  for (int t0 = 0; t0 < tmax; t0 += 32) {
    __syncthreads();
    {
      int r = tid >> 3, c = (tid & 7) * 8;
      *(uint4*)(&Ks[r * LDK + c]) =
          *(const uint4*)(base + (size_t)(t0 + r) * ld + 1024 + h * 64 + c);
    }
#pragma unroll
    for (int p = 0; p < 2; ++p) {
      int t = p * 16 + (tid >> 4);
      int d0 = (tid & 15) * 8;
      f16x8 v = *(const f16x8*)(base + (size_t)(t0 + t) * ld + 2048 + h * 128 + d0);
#pragma unroll
      for (int j = 0; j < 8; ++j) Vt[vt_off(d0 + j) + t] = v[j];
    }
    __syncthreads();

    // S = Q K^T  (two 16-col t-subtiles)
    f32x4 st[2][2];
#pragma unroll
    for (int m = 0; m < 2; ++m)
#pragma unroll
      for (int ts = 0; ts < 2; ++ts) st[m][ts] = (f32x4){0.f, 0.f, 0.f, 0.f};
#pragma unroll
    for (int ts = 0; ts < 2; ++ts) {
      f16x8 bk0 = *(const f16x8*)(&Ks[(ts * 16 + rm) * LDK + quad * 8]);
      f16x8 bk1 = *(const f16x8*)(&Ks[(ts * 16 + rm) * LDK + 32 + quad * 8]);
#pragma unroll
      for (int m = 0; m < 2; ++m) {
        st[m][ts] = MFMA_16x16x32(qa[m][0], bk0, st[m][ts]);
        st[m][ts] = MFMA_16x16x32(qa[m][1], bk1, st[m][ts]);
      }
    }
    // decay mask (recomputed, never loaded), denom accumulation, P -> LDS
#pragma unroll
    for (int m = 0; m < 2; ++m)
#pragma unroll
      for (int ts = 0; ts < 2; ++ts)
#pragma unroll
        for (int r = 0; r < 4; ++r) {
          int s = s_blk + w * 32 + m * 16 + quad * 4 + r;
          int t = t0 + ts * 16 + rm;
          int diff = s - t;
          float pv = 0.f;
          if (diff >= 0) pv = st[m][ts][r] * expf(logd * (float)diff);
          den[m][r] += pv;
          Ps[w][(m * 16 + quad * 4 + r) * LDP + ts * 16 + rm] = (f16)pv;
        }
    __syncthreads();
    // O += P V
    f16x8 pa0 = *(const f16x8*)(&Ps[w][rm * LDP + quad * 8]);
    f16x8 pa1 = *(const f16x8*)(&Ps[w][(16 + rm) * LDP + quad * 8]);
#pragma unroll
    for (int n = 0; n < 8; ++n) {
      f16x8 bv = *(const f16x8*)(&Vt[voff[n]]);
      od[0][n] = MFMA_16x16x32(pa0, bv, od[0][n]);
      od[1][n] = MFMA_16x16x32(pa1, bv, od[1][n]);
    }
  }

  // epilogue: denom -> divide -> RMS(hd=128) -> silu(g) gate -> act
#pragma unroll
  for (int m = 0; m < 2; ++m) {
    float dn[4], rr[4];
#pragma unroll
    for (int r = 0; r < 4; ++r) {
      float d = den[m][r];
      d += __shfl_xor(d, 1, 16);
      d += __shfl_xor(d, 2, 16);
      d += __shfl_xor(d, 4, 16);
      d += __shfl_xor(d, 8, 16);
      dn[r] = fmaxf(fabsf(d), 1.0f);
    }
    float ssq[4] = {0.f, 0.f, 0.f, 0.f};
#pragma unroll
    for (int n = 0; n < 8; ++n)
#pragma unroll
      for (int r = 0; r < 4; ++r) {
        float o = od[m][n][r] / dn[r];
        od[m][n][r] = o;
        ssq[r] += o * o;
      }
#pragma unroll
    for (int r = 0; r < 4; ++r) {
      float s2 = ssq[r];
      s2 += __shfl_xor(s2, 1, 16);
      s2 += __shfl_xor(s2, 2, 16);
      s2 += __shfl_xor(s2, 4, 16);
      s2 += __shfl_xor(s2, 8, 16);
      rr[r] = rsqrtf(s2 * (1.0f / 128.0f) + 1e-5f);
    }
#pragma unroll
    for (int n = 0; n < 8; ++n)
#pragma unroll
      for (int r = 0; r < 4; ++r) {
        int s = s_blk + w * 32 + m * 16 + quad * 4 + r;
        int dcol = n * 16 + rm;
        float g = (float)base[(size_t)s * ld + 4096 + h * 128 + dcol];
        float o = od[m][n][r] * rr[r];
        float a = (g / (1.0f + expf(-g))) * o;
        act[((size_t)b * 2048 + s) * 2048 + h * 128 + dcol] = (f16)a;
      }
  }
}

// ---------------------------------------------------------------- launch
extern "C" void kernel_launch(void* const* d_in, const int* in_sizes, int n_in,
                              void* d_out, int out_size, void* d_ws, size_t ws_size,
                              hipStream_t stream) {
  const float* x    = (const float*)d_in[0];
  const float* sinp = (const float*)d_in[1];
  const float* cosp = (const float*)d_in[2];
  // d_in[3] = mask : recomputed on the fly, never read (saves 256 MB of HBM traffic)
  const float* Wq = (const float*)d_in[4];
  const float* Wk = (const float*)d_in[5];
  const float* Wv = (const float*)d_in[6];
  const float* Wg = (const float*)d_in[7];
  const float* Wo = (const float*)d_in[8];
  float* out = (float*)d_out;

  char* ws = (char*)d_ws;
  f16* xh   = (f16*)(ws);                  // 4096*1024          =  8 MB
  f16* W1h  = (f16*)(ws + 8388608);        // 6144*1024          = 12.6 MB
  f16* Woh  = (f16*)(ws + 20971520);       // 1024*2048          =  4 MB
  f16* qkvg = (f16*)(ws + 25165824);       // 4096*6144          = 50 MB
  f16* acth = (f16*)(ws + 75497472);       // 4096*2048          = 16.8 MB  (total ~92 MB)

  k_cast_x <<<4096, 256, 0, stream>>>(x, xh);
  k_cast_w1<<<6144, 256, 0, stream>>>(Wq, Wk, Wv, Wg, W1h);
  k_cast_wo<<<2048, 256, 0, stream>>>(Wo, Woh);

  // qkvg = xh @ W1h^T   (M=4096, N=6144, K=1024)
  k_gemm_bt<f16><<<dim3(48, 32), 256, 0, stream>>>(xh, W1h, qkvg, 4096, 6144, 1024);

  // RoPE over q|k columns (first 2048 cols of each row)
  k_rope<<<16384, 256, 0, stream>>>(qkvg, sinp, cosp);

  // fused retention attention -> acth
  k_attn<<<dim3(16, 16, 2), 256, 0, stream>>>(qkvg, acth);

  // out = acth @ Woh^T  (M=4096, N=1024, K=2048)
  k_gemm_bt<float><<<dim3(8, 32), 256, 0, stream>>>(acth, Woh, out, 4096, 1024, 2048);
}

// Round 5
// 662.744 us; speedup vs baseline: 1.0433x; 1.0433x over previous
//
#include <hip/hip_runtime.h>

typedef _Float16 f16;
typedef _Float16 f16x2 __attribute__((ext_vector_type(2)));
typedef _Float16 f16x4 __attribute__((ext_vector_type(4)));
typedef _Float16 f16x8 __attribute__((ext_vector_type(8)));
typedef float f32x4 __attribute__((ext_vector_type(4)));

#define MFMA_16x16x32(a, b, c) __builtin_amdgcn_mfma_f32_16x16x32_f16((a), (b), (c), 0, 0, 0)

// B=2 S=2048 H=1024 HEADS=16 KD=64 VDIM=2048 HD=128; M=B*S=4096
// qkvg row: [q(1024) | k(1024) | v(2048) | g(2048)] = 6144 cols.

// ---------------------------------------------------------------- merged casts
__global__ void k_cast_all(const float* __restrict__ x, const float* __restrict__ Wq,
                           const float* __restrict__ Wk, const float* __restrict__ Wv,
                           const float* __restrict__ Wg, const float* __restrict__ Wo,
                           f16* __restrict__ xh, f16* __restrict__ W1h, f16* __restrict__ Woh) {
  size_t u = ((size_t)blockIdx.x * 256 + threadIdx.x) * 4;
  const float* src;
  f16* dst;
  float sc = 1.0f;
  if (u < 4194304) {                       // x: 4096x1024
    src = x + u; dst = xh + u;
  } else if (u < 10485760) {               // W1: 6144x1024 (q|k|v|g rows)
    size_t idx = u - 4194304;
    int row = (int)(idx >> 10), col = (int)(idx & 1023);
    if (row < 1024)      { src = Wq + (size_t)row * 1024 + col; }
    else if (row < 2048) { src = Wk + (size_t)(row - 1024) * 1024 + col; sc = 0.125f; } // kd^-0.5
    else if (row < 4096) { src = Wv + (size_t)(row - 2048) * 1024 + col; }
    else                 { src = Wg + (size_t)(row - 4096) * 1024 + col; }
    dst = W1h + idx;
  } else {                                 // Wo: 1024x2048
    size_t idx = u - 10485760;
    src = Wo + idx; dst = Woh + idx;
  }
  float4 v = *(const float4*)src;
  f16x4 r = { (f16)(v.x * sc), (f16)(v.y * sc), (f16)(v.z * sc), (f16)(v.w * sc) };
  *(f16x4*)dst = r;
}

// ---------------------------------------------------------------- GEMM (R1-proven register staging)
// C[m][n] = sum_k A[m][k]*Bw[n][k].  128 x NT tile, BK=64, 4 waves.
template <int NT, typename OutT>
__global__ __launch_bounds__(256, 2)
void k_gemm_bt(const f16* __restrict__ A, const f16* __restrict__ Bw,
               OutT* __restrict__ C, int M, int N, int K) {
  constexpr int LDT = 72;                  // 64 + 8 pad
  __shared__ f16 As[128 * LDT];
  __shared__ f16 Bs[NT * LDT];
  constexpr int NR = NT / 16;
  const int tid = threadIdx.x;
  const int lane = tid & 63, w = tid >> 6;
  const int quad = lane >> 4, rm = lane & 15;
  const int mt = blockIdx.y, nt = blockIdx.x;
  const f16* Ab = A + (size_t)mt * 128 * K;
  const f16* Bb = Bw + (size_t)nt * NT * K;
  f32x4 acc[2][NR] = {};

  const int r0 = tid >> 3;                 // 0..31
  const int c8 = (tid & 7) * 8;            // 0..56

  for (int k0 = 0; k0 < K; k0 += 64) {
    __syncthreads();
#pragma unroll
    for (int p = 0; p < 4; ++p) {          // A: 128 rows
      int r = r0 + p * 32;
      *(uint4*)(&As[r * LDT + c8]) = *(const uint4*)(Ab + (size_t)r * K + k0 + c8);
    }
#pragma unroll
    for (int p = 0; p < NT / 32; ++p) {    // B: NT rows
      int r = r0 + p * 32;
      *(uint4*)(&Bs[r * LDT + c8]) = *(const uint4*)(Bb + (size_t)r * K + k0 + c8);
    }
    __syncthreads();
#pragma unroll
    for (int kk = 0; kk < 64; kk += 32) {
      const int ko = kk + quad * 8;
      f16x8 a0 = *(const f16x8*)(&As[(w * 32 + rm) * LDT + ko]);
      f16x8 a1 = *(const f16x8*)(&As[(w * 32 + 16 + rm) * LDT + ko]);
#pragma unroll
      for (int n = 0; n < NR; ++n) {
        f16x8 bf = *(const f16x8*)(&Bs[(n * 16 + rm) * LDT + ko]);
        acc[0][n] = MFMA_16x16x32(a0, bf, acc[0][n]);
        acc[1][n] = MFMA_16x16x32(a1, bf, acc[1][n]);
      }
    }
  }
#pragma unroll
  for (int m = 0; m < 2; ++m)
#pragma unroll
    for (int n = 0; n < NR; ++n)
#pragma unroll
      for (int r = 0; r < 4; ++r) {
        int row = mt * 128 + w * 32 + m * 16 + quad * 4 + r;  // C/D: row=quad*4+reg
        int col = nt * NT + n * 16 + rm;                      //      col=lane&15
        C[(size_t)row * N + col] = (OutT)acc[m][n][r];
      }
}

// ---------------------------------------------------------------- RoPE on q,k halves (R1-verbatim)
__global__ void k_rope(f16* __restrict__ qkvg, const float* __restrict__ sinp,
                       const float* __restrict__ cosp) {
  int u = blockIdx.x * 256 + threadIdx.x;   // 4096 rows * 1024 pairs
  int row = u >> 10;
  int col = (u & 1023) * 2;                 // even col in [0,2048)
  int s = row & 2047;
  int d = col & 63;                          // index within head (kd=64)
  f16x2* p = (f16x2*)(qkvg + (size_t)row * 6144 + col);
  f16x2 xv = *p;
  float xe = (float)xv[0], xo = (float)xv[1];
  float se = sinp[s * 64 + d], so = sinp[s * 64 + d + 1];
  float ce = cosp[s * 64 + d], co = cosp[s * 64 + d + 1];
  f16x2 r = { (f16)(xe * ce - xo * se), (f16)(xo * co + xe * so) };
  *p = r;
}

// ---------------------------------------------------------------- fused retention attention (R1-verbatim)
__device__ __forceinline__ int vt_off(int d) { return d * 40 + (d >> 3) * 8; }  // skewed rows, 16B-aligned

__global__ __launch_bounds__(256, 2)
void k_attn(const f16* __restrict__ qkvg, f16* __restrict__ act) {
  constexpr int LDK = 72;
  constexpr int LDP = 40;
  __shared__ f16 Ks[32 * LDK];
  __shared__ f16 Vt[5240];            // Vt[d][t], row start = vt_off(d)
  __shared__ f16 Ps[4][32 * LDP];     // per-wave P staging (C-layout -> A-layout round trip)
  const int tid = threadIdx.x;
  const int lane = tid & 63, w = tid >> 6;
  const int quad = lane >> 4, rm = lane & 15;
  int bx = blockIdx.x;
  if (blockIdx.z) bx = 15 - bx;       // heavy+light pairing
  const int h = blockIdx.y, b = blockIdx.z;
  const int s_blk = bx * 128;
  const size_t ld = 6144;
  const f16* base = qkvg + (size_t)b * 2048 * ld;
  const float logd = logf(1.0f - exp2f(-5.0f - (float)h));

  f16x8 qa[2][2];
#pragma unroll
  for (int m = 0; m < 2; ++m) {
    int row = s_blk + w * 32 + m * 16 + rm;
#pragma unroll
    for (int kh = 0; kh < 2; ++kh)
      qa[m][kh] = *(const f16x8*)(base + (size_t)row * ld + h * 64 + kh * 32 + quad * 8);
  }
  int voff[8];
#pragma unroll
  for (int n = 0; n < 8; ++n) voff[n] = vt_off(n * 16 + rm) + quad * 8;

  f32x4 od[2][8];
#pragma unroll
  for (int m = 0; m < 2; ++m)
#pragma unroll
    for (int n = 0; n < 8; ++n) od[m][n] = (f32x4){0.f, 0.f, 0.f, 0.f};
  float den[2][4] = {{0.f, 0.f, 0.f, 0.f}, {0.f, 0.f, 0.f, 0.f}};

  const int tmax = s_blk + 128;
  for (int t0 = 0; t0 < tmax; t0 += 32) {
    __syncthreads();
    {
      int r = tid >> 3, c = (tid & 7) * 8;
      *(uint4*)(&Ks[r * LDK + c]) =
          *(const uint4*)(base + (size_t)(t0 + r) * ld + 1024 + h * 64 + c);
    }
#pragma unroll
    for (int p = 0; p < 2; ++p) {
      int t = p * 16 + (tid >> 4);
      int d0 = (tid & 15) * 8;
      f16x8 v = *(const f16x8*)(base + (size_t)(t0 + t) * ld + 2048 + h * 128 + d0);
#pragma unroll
      for (int j = 0; j < 8; ++j) Vt[vt_off(d0 + j) + t] = v[j];
    }
    __syncthreads();

    // S = Q K^T  (two 16-col t-subtiles)
    f32x4 st[2][2];
#pragma unroll
    for (int m = 0; m < 2; ++m)
#pragma unroll
      for (int ts = 0; ts < 2; ++ts) st[m][ts] = (f32x4){0.f, 0.f, 0.f, 0.f};
#pragma unroll
    for (int ts = 0; ts < 2; ++ts) {
      f16x8 bk0 = *(const f16x8*)(&Ks[(ts * 16 + rm) * LDK + quad * 8]);
      f16x8 bk1 = *(const f16x8*)(&Ks[(ts * 16 + rm) * LDK + 32 + quad * 8]);
#pragma unroll
      for (int m = 0; m < 2; ++m) {
        st[m][ts] = MFMA_16x16x32(qa[m][0], bk0, st[m][ts]);
        st[m][ts] = MFMA_16x16x32(qa[m][1], bk1, st[m][ts]);
      }
    }
    // decay mask (recomputed, never loaded), denom accumulation, P -> LDS
#pragma unroll
    for (int m = 0; m < 2; ++m)
#pragma unroll
      for (int ts = 0; ts < 2; ++ts)
#pragma unroll
        for (int r = 0; r < 4; ++r) {
          int s = s_blk + w * 32 + m * 16 + quad * 4 + r;
          int t = t0 + ts * 16 + rm;
          int diff = s - t;
          float pv = 0.f;
          if (diff >= 0) pv = st[m][ts][r] * expf(logd * (float)diff);
          den[m][r] += pv;
          Ps[w][(m * 16 + quad * 4 + r) * LDP + ts * 16 + rm] = (f16)pv;
        }
    __syncthreads();
    // O += P V
    f16x8 pa0 = *(const f16x8*)(&Ps[w][rm * LDP + quad * 8]);
    f16x8 pa1 = *(const f16x8*)(&Ps[w][(16 + rm) * LDP + quad * 8]);
#pragma unroll
    for (int n = 0; n < 8; ++n) {
      f16x8 bv = *(const f16x8*)(&Vt[voff[n]]);
      od[0][n] = MFMA_16x16x32(pa0, bv, od[0][n]);
      od[1][n] = MFMA_16x16x32(pa1, bv, od[1][n]);
    }
  }

  // epilogue: denom -> divide -> RMS(hd=128) -> silu(g) gate -> act
#pragma unroll
  for (int m = 0; m < 2; ++m) {
    float dn[4], rr[4];
#pragma unroll
    for (int r = 0; r < 4; ++r) {
      float d = den[m][r];
      d += __shfl_xor(d, 1, 16);
      d += __shfl_xor(d, 2, 16);
      d += __shfl_xor(d, 4, 16);
      d += __shfl_xor(d, 8, 16);
      dn[r] = fmaxf(fabsf(d), 1.0f);
    }
    float ssq[4] = {0.f, 0.f, 0.f, 0.f};
#pragma unroll
    for (int n = 0; n < 8; ++n)
#pragma unroll
      for (int r = 0; r < 4; ++r) {
        float o = od[m][n][r] / dn[r];
        od[m][n][r] = o;
        ssq[r] += o * o;
      }
#pragma unroll
    for (int r = 0; r < 4; ++r) {
      float s2 = ssq[r];
      s2 += __shfl_xor(s2, 1, 16);
      s2 += __shfl_xor(s2, 2, 16);
      s2 += __shfl_xor(s2, 4, 16);
      s2 += __shfl_xor(s2, 8, 16);
      rr[r] = rsqrtf(s2 * (1.0f / 128.0f) + 1e-5f);
    }
#pragma unroll
    for (int n = 0; n < 8; ++n)
#pragma unroll
      for (int r = 0; r < 4; ++r) {
        int s = s_blk + w * 32 + m * 16 + quad * 4 + r;
        int dcol = n * 16 + rm;
        float g = (float)base[(size_t)s * ld + 4096 + h * 128 + dcol];
        float o = od[m][n][r] * rr[r];
        float a = (g / (1.0f + expf(-g))) * o;
        act[((size_t)b * 2048 + s) * 2048 + h * 128 + dcol] = (f16)a;
      }
  }
}

// ---------------------------------------------------------------- launch
extern "C" void kernel_launch(void* const* d_in, const int* in_sizes, int n_in,
                              void* d_out, int out_size, void* d_ws, size_t ws_size,
                              hipStream_t stream) {
  const float* x    = (const float*)d_in[0];
  const float* sinp = (const float*)d_in[1];
  const float* cosp = (const float*)d_in[2];
  // d_in[3] = mask : recomputed on the fly, never read
  const float* Wq = (const float*)d_in[4];
  const float* Wk = (const float*)d_in[5];
  const float* Wv = (const float*)d_in[6];
  const float* Wg = (const float*)d_in[7];
  const float* Wo = (const float*)d_in[8];
  float* out = (float*)d_out;

  char* ws = (char*)d_ws;
  f16* xh   = (f16*)(ws);                  // 4096*1024
  f16* W1h  = (f16*)(ws + 8388608);        // 6144*1024
  f16* Woh  = (f16*)(ws + 20971520);       // 1024*2048
  f16* qkvg = (f16*)(ws + 25165824);       // 4096*6144
  f16* acth = (f16*)(ws + 75497472);       // 4096*2048

  k_cast_all<<<12288, 256, 0, stream>>>(x, Wq, Wk, Wv, Wg, Wo, xh, W1h, Woh);

  // qkvg = xh @ W1h^T   (M=4096, N=6144, K=1024)
  k_gemm_bt<128, f16><<<dim3(48, 32), 256, 0, stream>>>(xh, W1h, qkvg, 4096, 6144, 1024);

  // RoPE over q|k columns (first 2048 cols of each row)
  k_rope<<<16384, 256, 0, stream>>>(qkvg, sinp, cosp);

  // fused retention attention -> acth
  k_attn<<<dim3(16, 16, 2), 256, 0, stream>>>(qkvg, acth);

  // out = acth @ Woh^T  (M=4096, N=1024, K=2048)
  k_gemm_bt<64, float><<<dim3(16, 32), 256, 0, stream>>>(acth, Woh, out, 4096, 1024, 2048);
}

// Round 6
// 585.769 us; speedup vs baseline: 1.1804x; 1.1314x over previous
//
#include <hip/hip_runtime.h>

typedef _Float16 f16;
typedef _Float16 f16x2 __attribute__((ext_vector_type(2)));
typedef _Float16 f16x4 __attribute__((ext_vector_type(4)));
typedef _Float16 f16x8 __attribute__((ext_vector_type(8)));
typedef float f32x4 __attribute__((ext_vector_type(4)));

#define MFMA_16x16x32(a, b, c) __builtin_amdgcn_mfma_f32_16x16x32_f16((a), (b), (c), 0, 0, 0)

// B=2 S=2048 H=1024 HEADS=16 KD=64 VDIM=2048 HD=128; M=B*S=4096
// qkvg row: [q(1024) | k(1024) | v(2048) | g(2048)] = 6144 cols.

// async global->LDS, 16B per lane; LDS dest = wave-uniform base + lane*16 (m97/m104 semantics)
__device__ __forceinline__ void async_ld16(const void* g, void* l) {
  __builtin_amdgcn_global_load_lds((const __attribute__((address_space(1))) unsigned int*)g,
                                   (__attribute__((address_space(3))) unsigned int*)l,
                                   16, 0, 0);
}

// ---------------------------------------------------------------- merged casts
__global__ void k_cast_all(const float* __restrict__ x, const float* __restrict__ Wq,
                           const float* __restrict__ Wk, const float* __restrict__ Wv,
                           const float* __restrict__ Wg, const float* __restrict__ Wo,
                           f16* __restrict__ xh, f16* __restrict__ W1h, f16* __restrict__ Woh) {
  size_t u = ((size_t)blockIdx.x * 256 + threadIdx.x) * 4;
  const float* src;
  f16* dst;
  float sc = 1.0f;
  if (u < 4194304) {                       // x: 4096x1024
    src = x + u; dst = xh + u;
  } else if (u < 10485760) {               // W1: 6144x1024 (q|k|v|g rows)
    size_t idx = u - 4194304;
    int row = (int)(idx >> 10), col = (int)(idx & 1023);
    if (row < 1024)      { src = Wq + (size_t)row * 1024 + col; }
    else if (row < 2048) { src = Wk + (size_t)(row - 1024) * 1024 + col; sc = 0.125f; } // kd^-0.5
    else if (row < 4096) { src = Wv + (size_t)(row - 2048) * 1024 + col; }
    else                 { src = Wg + (size_t)(row - 4096) * 1024 + col; }
    dst = W1h + idx;
  } else {                                 // Wo: 1024x2048
    size_t idx = u - 10485760;
    src = Wo + idx; dst = Woh + idx;
  }
  float4 v = *(const float4*)src;
  f16x4 r = { (f16)(v.x * sc), (f16)(v.y * sc), (f16)(v.z * sc), (f16)(v.w * sc) };
  *(f16x4*)dst = r;
}

// ---------------------------------------------------------------- GEMM (m97 async-staged pattern)
// C[m][n] = sum_k A[m][k]*Bw[n][k].  128 x NT tile, BK=64, 4 waves, global_load_lds w16.
// Staging: lane l covers global (row = base8 + (l>>3), colgrp = l&7); deposit = base + l*16B
// lands at As[(base8 + (l>>3))*64 + (l&7)*8]  ==  LDS[r][c] = global[r][c].  Unpadded (m97).
template <int NT, typename OutT>
__global__ __launch_bounds__(256, 2)
void k_gemm_bt(const f16* __restrict__ A, const f16* __restrict__ Bw,
               OutT* __restrict__ C, int M, int N, int K) {
  __shared__ f16 As[128 * 64];
  __shared__ f16 Bs[NT * 64];
  constexpr int NR = NT / 16;
  const int tid = threadIdx.x;
  const int lane = tid & 63, w = tid >> 6;
  const int quad = lane >> 4, rm = lane & 15;
  const int mt = blockIdx.y, nt = blockIdx.x;
  const f16* Ab = A + (size_t)mt * 128 * K;
  const f16* Bb = Bw + (size_t)nt * NT * K;
  f32x4 acc[2][NR] = {};

  const int sr = lane >> 3;                // row within 8-row staging group
  const int sc8 = (lane & 7) * 8;          // col group * 8

  for (int k0 = 0; k0 < K; k0 += 64) {
    __syncthreads();
#pragma unroll
    for (int p = 0; p < 4; ++p) {          // A: wave w stages rows w*32 .. w*32+31
      int br = w * 32 + p * 8;
      async_ld16(Ab + (size_t)(br + sr) * K + k0 + sc8, &As[br * 64]);
    }
#pragma unroll
    for (int p = 0; p < NT / 32; ++p) {    // B: NT rows cooperatively
      int br = w * (NT / 4) + p * 8;
      async_ld16(Bb + (size_t)(br + sr) * K + k0 + sc8, &Bs[br * 64]);
    }
    __syncthreads();                       // emits s_waitcnt vmcnt(0) -> drains global_load_lds
#pragma unroll
    for (int kk = 0; kk < 64; kk += 32) {
      const int ko = kk + quad * 8;
      f16x8 a0 = *(const f16x8*)(&As[(w * 32 + rm) * 64 + ko]);
      f16x8 a1 = *(const f16x8*)(&As[(w * 32 + 16 + rm) * 64 + ko]);
#pragma unroll
      for (int n = 0; n < NR; ++n) {
        f16x8 bf = *(const f16x8*)(&Bs[(n * 16 + rm) * 64 + ko]);
        acc[0][n] = MFMA_16x16x32(a0, bf, acc[0][n]);
        acc[1][n] = MFMA_16x16x32(a1, bf, acc[1][n]);
      }
    }
  }
#pragma unroll
  for (int m = 0; m < 2; ++m)
#pragma unroll
    for (int n = 0; n < NR; ++n)
#pragma unroll
      for (int r = 0; r < 4; ++r) {
        int row = mt * 128 + w * 32 + m * 16 + quad * 4 + r;  // C/D: row=quad*4+reg
        int col = nt * NT + n * 16 + rm;                      //      col=lane&15
        C[(size_t)row * N + col] = (OutT)acc[m][n][r];
      }
}

// ---------------------------------------------------------------- RoPE on q,k halves (R1-verbatim)
__global__ void k_rope(f16* __restrict__ qkvg, const float* __restrict__ sinp,
                       const float* __restrict__ cosp) {
  int u = blockIdx.x * 256 + threadIdx.x;   // 4096 rows * 1024 pairs
  int row = u >> 10;
  int col = (u & 1023) * 2;                 // even col in [0,2048)
  int s = row & 2047;
  int d = col & 63;                          // index within head (kd=64)
  f16x2* p = (f16x2*)(qkvg + (size_t)row * 6144 + col);
  f16x2 xv = *p;
  float xe = (float)xv[0], xo = (float)xv[1];
  float se = sinp[s * 64 + d], so = sinp[s * 64 + d + 1];
  float ce = cosp[s * 64 + d], co = cosp[s * 64 + d + 1];
  f16x2 r = { (f16)(xe * ce - xo * se), (f16)(xo * co + xe * so) };
  *p = r;
}

// ---------------------------------------------------------------- fused retention attention (R1-verbatim)
__device__ __forceinline__ int vt_off(int d) { return d * 40 + (d >> 3) * 8; }  // skewed rows, 16B-aligned

__global__ __launch_bounds__(256, 2)
void k_attn(const f16* __restrict__ qkvg, f16* __restrict__ act) {
  constexpr int LDK = 72;
  constexpr int LDP = 40;
  __shared__ f16 Ks[32 * LDK];
  __shared__ f16 Vt[5240];            // Vt[d][t], row start = vt_off(d)
  __shared__ f16 Ps[4][32 * LDP];     // per-wave P staging (C-layout -> A-layout round trip)
  const int tid = threadIdx.x;
  const int lane = tid & 63, w = tid >> 6;
  const int quad = lane >> 4, rm = lane & 15;
  int bx = blockIdx.x;
  if (blockIdx.z) bx = 15 - bx;       // heavy+light pairing
  const int h = blockIdx.y, b = blockIdx.z;
  const int s_blk = bx * 128;
  const size_t ld = 6144;
  const f16* base = qkvg + (size_t)b * 2048 * ld;
  const float logd = logf(1.0f - exp2f(-5.0f - (float)h));

  f16x8 qa[2][2];
#pragma unroll
  for (int m = 0; m < 2; ++m) {
    int row = s_blk + w * 32 + m * 16 + rm;
#pragma unroll
    for (int kh = 0; kh < 2; ++kh)
      qa[m][kh] = *(const f16x8*)(base + (size_t)row * ld + h * 64 + kh * 32 + quad * 8);
  }
  int voff[8];
#pragma unroll
  for (int n = 0; n < 8; ++n) voff[n] = vt_off(n * 16 + rm) + quad * 8;

  f32x4 od[2][8];
#pragma unroll
  for (int m = 0; m < 2; ++m)
#pragma unroll
    for (int n = 0; n < 8; ++n) od[m][n] = (f32x4){0.f, 0.f, 0.f, 0.f};
  float den[2][4] = {{0.f, 0.f, 0.f, 0.f}, {0.f, 0.f, 0.f, 0.f}};

  const int tmax = s_blk + 128;
  for (int t0 = 0; t0 < tmax; t0 += 32) {
    __syncthreads();
    {
      int r = tid >> 3, c = (tid & 7) * 8;
      *(uint4*)(&Ks[r * LDK + c]) =
          *(const uint4*)(base + (size_t)(t0 + r) * ld + 1024 + h * 64 + c);
    }
#pragma unroll
    for (int p = 0; p < 2; ++p) {
      int t = p * 16 + (tid >> 4);
      int d0 = (tid & 15) * 8;
      f16x8 v = *(const f16x8*)(base + (size_t)(t0 + t) * ld + 2048 + h * 128 + d0);
#pragma unroll
      for (int j = 0; j < 8; ++j) Vt[vt_off(d0 + j) + t] = v[j];
    }
    __syncthreads();

    // S = Q K^T  (two 16-col t-subtiles)
    f32x4 st[2][2];
#pragma unroll
    for (int m = 0; m < 2; ++m)
#pragma unroll
      for (int ts = 0; ts < 2; ++ts) st[m][ts] = (f32x4){0.f, 0.f, 0.f, 0.f};
#pragma unroll
    for (int ts = 0; ts < 2; ++ts) {
      f16x8 bk0 = *(const f16x8*)(&Ks[(ts * 16 + rm) * LDK + quad * 8]);
      f16x8 bk1 = *(const f16x8*)(&Ks[(ts * 16 + rm) * LDK + 32 + quad * 8]);
#pragma unroll
      for (int m = 0; m < 2; ++m) {
        st[m][ts] = MFMA_16x16x32(qa[m][0], bk0, st[m][ts]);
        st[m][ts] = MFMA_16x16x32(qa[m][1], bk1, st[m][ts]);
      }
    }
    // decay mask (recomputed, never loaded), denom accumulation, P -> LDS
#pragma unroll
    for (int m = 0; m < 2; ++m)
#pragma unroll
      for (int ts = 0; ts < 2; ++ts)
#pragma unroll
        for (int r = 0; r < 4; ++r) {
          int s = s_blk + w * 32 + m * 16 + quad * 4 + r;
          int t = t0 + ts * 16 + rm;
          int diff = s - t;
          float pv = 0.f;
          if (diff >= 0) pv = st[m][ts][r] * expf(logd * (float)diff);
          den[m][r] += pv;
          Ps[w][(m * 16 + quad * 4 + r) * LDP + ts * 16 + rm] = (f16)pv;
        }
    __syncthreads();
    // O += P V
    f16x8 pa0 = *(const f16x8*)(&Ps[w][rm * LDP + quad * 8]);
    f16x8 pa1 = *(const f16x8*)(&Ps[w][(16 + rm) * LDP + quad * 8]);
#pragma unroll
    for (int n = 0; n < 8; ++n) {
      f16x8 bv = *(const f16x8*)(&Vt[voff[n]]);
      od[0][n] = MFMA_16x16x32(pa0, bv, od[0][n]);
      od[1][n] = MFMA_16x16x32(pa1, bv, od[1][n]);
    }
  }

  // epilogue: denom -> divide -> RMS(hd=128) -> silu(g) gate -> act
#pragma unroll
  for (int m = 0; m < 2; ++m) {
    float dn[4], rr[4];
#pragma unroll
    for (int r = 0; r < 4; ++r) {
      float d = den[m][r];
      d += __shfl_xor(d, 1, 16);
      d += __shfl_xor(d, 2, 16);
      d += __shfl_xor(d, 4, 16);
      d += __shfl_xor(d, 8, 16);
      dn[r] = fmaxf(fabsf(d), 1.0f);
    }
    float ssq[4] = {0.f, 0.f, 0.f, 0.f};
#pragma unroll
    for (int n = 0; n < 8; ++n)
#pragma unroll
      for (int r = 0; r < 4; ++r) {
        float o = od[m][n][r] / dn[r];
        od[m][n][r] = o;
        ssq[r] += o * o;
      }
#pragma unroll
    for (int r = 0; r < 4; ++r) {
      float s2 = ssq[r];
      s2 += __shfl_xor(s2, 1, 16);
      s2 += __shfl_xor(s2, 2, 16);
      s2 += __shfl_xor(s2, 4, 16);
      s2 += __shfl_xor(s2, 8, 16);
      rr[r] = rsqrtf(s2 * (1.0f / 128.0f) + 1e-5f);
    }
#pragma unroll
    for (int n = 0; n < 8; ++n)
#pragma unroll
      for (int r = 0; r < 4; ++r) {
        int s = s_blk + w * 32 + m * 16 + quad * 4 + r;
        int dcol = n * 16 + rm;
        float g = (float)base[(size_t)s * ld + 4096 + h * 128 + dcol];
        float o = od[m][n][r] * rr[r];
        float a = (g / (1.0f + expf(-g))) * o;
        act[((size_t)b * 2048 + s) * 2048 + h * 128 + dcol] = (f16)a;
      }
  }
}

// ---------------------------------------------------------------- launch
extern "C" void kernel_launch(void* const* d_in, const int* in_sizes, int n_in,
                              void* d_out, int out_size, void* d_ws, size_t ws_size,
                              hipStream_t stream) {
  const float* x    = (const float*)d_in[0];
  const float* sinp = (const float*)d_in[1];
  const float* cosp = (const float*)d_in[2];
  // d_in[3] = mask : recomputed on the fly, never read
  const float* Wq = (const float*)d_in[4];
  const float* Wk = (const float*)d_in[5];
  const float* Wv = (const float*)d_in[6];
  const float* Wg = (const float*)d_in[7];
  const float* Wo = (const float*)d_in[8];
  float* out = (float*)d_out;

  char* ws = (char*)d_ws;
  f16* xh   = (f16*)(ws);                  // 4096*1024
  f16* W1h  = (f16*)(ws + 8388608);        // 6144*1024
  f16* Woh  = (f16*)(ws + 20971520);       // 1024*2048
  f16* qkvg = (f16*)(ws + 25165824);       // 4096*6144
  f16* acth = (f16*)(ws + 75497472);       // 4096*2048

  k_cast_all<<<12288, 256, 0, stream>>>(x, Wq, Wk, Wv, Wg, Wo, xh, W1h, Woh);

  // qkvg = xh @ W1h^T   (M=4096, N=6144, K=1024)
  k_gemm_bt<128, f16><<<dim3(48, 32), 256, 0, stream>>>(xh, W1h, qkvg, 4096, 6144, 1024);

  // RoPE over q|k columns (first 2048 cols of each row)
  k_rope<<<16384, 256, 0, stream>>>(qkvg, sinp, cosp);

  // fused retention attention -> acth
  k_attn<<<dim3(16, 16, 2), 256, 0, stream>>>(qkvg, acth);

  // out = acth @ Woh^T  (M=4096, N=1024, K=2048)
  k_gemm_bt<64, float><<<dim3(16, 32), 256, 0, stream>>>(acth, Woh, out, 4096, 1024, 2048);
}